// Round 4
// baseline (621.525 us; speedup 1.0000x reference)
//
#include <hip/hip_runtime.h>
#include <cmath>

typedef unsigned short u16;
using short8 = __attribute__((ext_vector_type(8))) short;   // 8 x bf16
using f32x4  = __attribute__((ext_vector_type(4))) float;   // MFMA acc

// ---------- helpers ----------
__device__ __forceinline__ u16 f2bf(float f) {  // fp32 -> bf16 RNE
  union { float f; unsigned u; } c; c.f = f;
  unsigned r = c.u + 0x7fffu + ((c.u >> 16) & 1u);
  return (u16)(r >> 16);
}
__device__ __forceinline__ float bf2f(u16 b) {
  union { unsigned u; float f; } c; c.u = ((unsigned)b) << 16;
  return c.f;
}

__device__ __forceinline__ void gld_lds16(void* lds, const void* g) {
  __builtin_amdgcn_global_load_lds(
      (const __attribute__((address_space(1))) void*)g,
      (__attribute__((address_space(3))) void*)lds, 16, 0, 0);
}

// ---------- fp32 -> bf16 convert ----------
__global__ __launch_bounds__(256) void cvt_bf16(const float* __restrict__ in,
                                                u16* __restrict__ out, int n4) {
  int i = blockIdx.x * 256 + threadIdx.x;
  if (i >= n4) return;
  float4 v = ((const float4*)in)[i];
  ushort4 o;
  o.x = f2bf(v.x); o.y = f2bf(v.y); o.z = f2bf(v.z); o.w = f2bf(v.w);
  ((ushort4*)out)[i] = o;
}

// fp32 -> bf16 into strided (padded) rows
__global__ __launch_bounds__(256) void cvt_pad(const float* __restrict__ in,
                                               u16* __restrict__ out,
                                               int incols4, int outstride, int n4) {
  int i = blockIdx.x * 256 + threadIdx.x;
  if (i >= n4) return;
  int row = i / incols4, c = i - row * incols4;
  float4 v = ((const float4*)in)[i];
  ushort4 o;
  o.x = f2bf(v.x); o.y = f2bf(v.y); o.z = f2bf(v.z); o.w = f2bf(v.w);
  *(ushort4*)&out[(size_t)row * outstride + c * 4] = o;
}

// ---------- relative-position bias table ----------
__global__ __launch_bounds__(256) void btab_kernel(const float* __restrict__ rel_embed,
                                                   float* __restrict__ btab) {
  int idx = blockIdx.x * 256 + threadIdx.x;
  if (idx >= 16 * 2048) return;
  int h = idx >> 11;
  int d = idx & 2047;
  if (d >= 2047) return;
  int rel = d - 1023;
  int bucket = (rel > 0) ? 160 : 0;
  int ar = rel < 0 ? -rel : rel;
  if (ar < 80) {
    bucket += ar;
  } else {
    int large = 80 + (int)(logf((float)ar / 80.0f) / 2.3025851f * 80.0f);
    if (large > 159) large = 159;
    bucket += large;
  }
  btab[h * 2048 + d] = rel_embed[bucket * 16 + h];
}

// ---------- gate ----------
__global__ __launch_bounds__(256) void gate_kernel(const float* __restrict__ x,
                                                   const float* __restrict__ Wg,
                                                   const float* __restrict__ bg,
                                                   const float* __restrict__ gc,
                                                   float* __restrict__ gate_out) {
  int gw = blockIdx.x * 4 + (threadIdx.x >> 6);
  int lane = threadIdx.x & 63;
  int s = gw & 1023, bh = gw >> 10, b = bh >> 4, h = bh & 15;
  float wA = Wg[lane] + Wg[64 + lane] + Wg[128 + lane] + Wg[192 + lane];
  float wB = Wg[256 + lane] + Wg[320 + lane] + Wg[384 + lane] + Wg[448 + lane];
  float xv = x[((size_t)(b * 1024 + s)) * 1024 + h * 64 + lane];
  float pa = xv * wA, pb = xv * wB;
  #pragma unroll
  for (int m = 1; m < 64; m <<= 1) {
    pa += __shfl_xor(pa, m, 64);
    pb += __shfl_xor(pb, m, 64);
  }
  if (lane == 0) {
    float bgA = bg[0] + bg[1] + bg[2] + bg[3];
    float bgB = bg[4] + bg[5] + bg[6] + bg[7];
    float ga = 1.f / (1.f + expf(-(pa + bgA)));
    float gb = 1.f / (1.f + expf(-(pb + bgB)));
    gate_out[(size_t)bh * 1024 + s] = ga * (gb * gc[h] - 1.f) + 2.f;
  }
}

// ---------- V transpose: vt[bh][d][s] ----------
__global__ __launch_bounds__(256) void vtrans_kernel(const u16* __restrict__ vb,
                                                     u16* __restrict__ vt) {
  __shared__ u16 tile[64 * 65];
  int bh = blockIdx.y, b = bh >> 4, h = bh & 15;
  int s0 = blockIdx.x * 64;
  int tid = threadIdx.x;
  int r = tid >> 3, c = (tid & 7) * 8;
  #pragma unroll
  for (int p = 0; p < 2; ++p) {
    int s = p * 32 + r;
    uint4 vv = *(const uint4*)&vb[((size_t)(b * 1024 + s0 + s)) * 1024 + h * 64 + c];
    const u16* pv = (const u16*)&vv;
    #pragma unroll
    for (int e = 0; e < 8; ++e) tile[(c + e) * 65 + s] = pv[e];
  }
  __syncthreads();
  int d = tid & 63, jc0 = tid >> 6;
  #pragma unroll
  for (int jc = jc0; jc < 8; jc += 4) {
    u16 tmp[8];
    #pragma unroll
    for (int e = 0; e < 8; ++e) tmp[e] = tile[d * 65 + jc * 8 + e];
    *(uint4*)&vt[((size_t)(bh * 64 + d)) * 1024 + s0 + jc * 8] = *(uint4*)tmp;
  }
}

// ---------- GEMM: 256x128 tile, 3-stage pipeline, 1 barrier/step ----------
// C[m,n] = sum_k A[m,k]*Bw[n,k]. Wave w: 128M x 64N (acc 8x4 16x16 tiles).
// Pipeline: prefetch depth 2 via 3 LDS buffers; loads for step k+2 issued
// AFTER barrier(k); s_waitcnt vmcnt(6) mid-loop (never 0). Single barrier:
// a wave passing barrier(k+1) has consumed buf[k%3] (MFMA issue precedes
// barrier in program order), and buf[k%3] is only rewritten after it.
// MODE 0: QKV (bias + q*0.125, bf16 x3)
// MODE 2: gelu/elu -> ffadp (stride 4352)
// MODE 3: fp32 partial store (z partials, stride 4M floats)
template <int MODE>
__global__ __launch_bounds__(256, 2) void gemm_bt(
    const u16* __restrict__ A, const u16* __restrict__ Bw,
    int K, int Ksub, int N,
    const float* __restrict__ bias0, const float* __restrict__ bias1,
    const float* __restrict__ bias2,
    float* __restrict__ outf,
    u16* __restrict__ ob0, u16* __restrict__ ob1, u16* __restrict__ ob2) {
  __shared__ __align__(16) u16 As[3][256 * 32];
  __shared__ __align__(16) u16 Bs[3][128 * 32];
  const int tid = threadIdx.x;
  const int lane = tid & 63, wave = tid >> 6;
  const int quad = lane >> 4, l16 = lane & 15;
  const int bm = blockIdx.x * 256, bn = blockIdx.y * 128;
  const int kz = blockIdx.z;
  const int nsteps = Ksub >> 5;
  const int sr = lane & 15, skc = (lane >> 4) * 8;

  const u16* a0 = A + (size_t)(bm + wave * 64 + sr) * K + kz * Ksub + skc;
  const u16* b0 = Bw + (size_t)(bn + wave * 32 + sr) * K + kz * Ksub + skc;
  const size_t ra = (size_t)16 * K;

  f32x4 acc[8][4] = {};

  // prologue: steps 0,1 -> bufs 0,1
  #pragma unroll
  for (int t = 0; t < 4; ++t) gld_lds16(&As[0][(wave * 4 + t) * 512], a0 + t * ra);
  #pragma unroll
  for (int t = 0; t < 2; ++t) gld_lds16(&Bs[0][(wave * 2 + t) * 512], b0 + t * ra);
  if (nsteps > 1) {
    #pragma unroll
    for (int t = 0; t < 4; ++t) gld_lds16(&As[1][(wave * 4 + t) * 512], a0 + t * ra + 32);
    #pragma unroll
    for (int t = 0; t < 2; ++t) gld_lds16(&Bs[1][(wave * 2 + t) * 512], b0 + t * ra + 32);
  }

  int cur = 0, nxt2 = 2;
  for (int ks = 0; ks < nsteps; ++ks) {
    if (ks + 1 < nsteps) asm volatile("s_waitcnt vmcnt(6)" ::: "memory");
    else                 asm volatile("s_waitcnt vmcnt(0)" ::: "memory");
    __builtin_amdgcn_s_barrier();
    if (ks + 2 < nsteps) {
      int ko = (ks + 2) * 32;
      #pragma unroll
      for (int t = 0; t < 4; ++t) gld_lds16(&As[nxt2][(wave * 4 + t) * 512], a0 + t * ra + ko);
      #pragma unroll
      for (int t = 0; t < 2; ++t) gld_lds16(&Bs[nxt2][(wave * 2 + t) * 512], b0 + t * ra + ko);
    }
    const u16* Ap = As[cur];
    const u16* Bp = Bs[cur];
    short8 af[8], bf[4];
    #pragma unroll
    for (int mi = 0; mi < 8; ++mi)
      af[mi] = *(const short8*)&Ap[((wave & 1) * 8 + mi) * 512 + quad * 128 + l16 * 8];
    #pragma unroll
    for (int ni = 0; ni < 4; ++ni)
      bf[ni] = *(const short8*)&Bp[((wave >> 1) * 4 + ni) * 512 + quad * 128 + l16 * 8];
    #pragma unroll
    for (int mi = 0; mi < 8; ++mi)
      #pragma unroll
      for (int ni = 0; ni < 4; ++ni)
        acc[mi][ni] = __builtin_amdgcn_mfma_f32_16x16x32_bf16(af[mi], bf[ni], acc[mi][ni], 0, 0, 0);
    cur = (cur == 2) ? 0 : cur + 1;
    nxt2 = (nxt2 == 2) ? 0 : nxt2 + 1;
  }

  float* outp = outf + (size_t)kz * 4194304;   // 16MB partial stride

  #pragma unroll
  for (int mi = 0; mi < 8; ++mi) {
    #pragma unroll
    for (int ni = 0; ni < 4; ++ni) {
      int col = bn + (wave >> 1) * 64 + ni * 16 + l16;
      #pragma unroll
      for (int r = 0; r < 4; ++r) {
        int m = bm + (wave & 1) * 128 + mi * 16 + quad * 4 + r;
        float v = acc[mi][ni][r];
        if constexpr (MODE == 0) {
          int seg = col >> 10;
          int nloc = col & 1023;
          const float* bs = seg == 0 ? bias0 : (seg == 1 ? bias1 : bias2);
          u16* dst = seg == 0 ? ob0 : (seg == 1 ? ob1 : ob2);
          v += bs[nloc];
          if (seg == 0) v *= 0.125f;
          dst[(size_t)m * 1024 + nloc] = f2bf(v);
        } else if constexpr (MODE == 2) {
          if (col < 4096) {
            float t = v + bias0[col];
            float g = 0.5f * t * (1.f + erff(t * 0.70710678118f));
            ob0[(size_t)m * 4352 + col] = f2bf(g);
          } else {
            float t = v + bias1[col - 4096];
            float e = t > 0.f ? t : expm1f(t);
            ob0[(size_t)m * 4352 + col] = f2bf(e);
          }
        } else {
          outp[(size_t)m * N + col] = v;
        }
      }
    }
  }
}

// ---------- flash attention (conflict-free LDS) ----------
__global__ __launch_bounds__(256) void attn_kernel(
    const u16* __restrict__ qb, const u16* __restrict__ kb, const u16* __restrict__ vt,
    const float* __restrict__ gate, const float* __restrict__ btab,
    u16* __restrict__ ctxb) {
  __shared__ __align__(16) u16 Qs[64 * 64];
  __shared__ __align__(16) u16 Ks[64 * 64];
  __shared__ __align__(16) u16 Vs[64 * 64];
  __shared__ __align__(16) u16 Ps[4][16 * 64];
  __shared__ u16 btl[2048];
  __shared__ float gbuf[64];

  const int tid = threadIdx.x;
  const int lane = tid & 63, wave = tid >> 6;
  const int quad = lane >> 4, l16 = lane & 15;
  const int it0 = blockIdx.x * 64;
  const int bh = blockIdx.y, b = bh >> 4, h = bh & 15;
  const int sr = lane & 15;
  const int skc = (lane >> 4) * 8;

  for (int idx = tid; idx < 2047; idx += 256) btl[idx] = f2bf(btab[h * 2048 + idx]);
  if (tid < 64) gbuf[tid] = gate[(size_t)bh * 1024 + it0 + tid];

  #pragma unroll
  for (int hf = 0; hf < 2; ++hf)
    gld_lds16(&Qs[wave * 1024 + hf * 512],
              &qb[((size_t)(b * 1024 + it0 + wave * 16 + sr)) * 1024 + h * 64 + hf * 32 + skc]);

  f32x4 oacc[4] = {};
  float mrow[4], lrow[4];
  #pragma unroll
  for (int r = 0; r < 4; ++r) { mrow[r] = -1e30f; lrow[r] = 0.f; }

  __syncthreads();

  for (int jt = 0; jt < 16; ++jt) {
    int j0 = jt * 64;
    #pragma unroll
    for (int hf = 0; hf < 2; ++hf) {
      gld_lds16(&Ks[wave * 1024 + hf * 512],
                &kb[((size_t)(b * 1024 + j0 + wave * 16 + sr)) * 1024 + h * 64 + hf * 32 + skc]);
      gld_lds16(&Vs[wave * 1024 + hf * 512],
                &vt[((size_t)(bh * 64 + wave * 16 + sr)) * 1024 + j0 + hf * 32 + skc]);
    }
    __syncthreads();

    f32x4 sacc[4] = {};
    #pragma unroll
    for (int c = 0; c < 2; ++c) {
      short8 aq = *(const short8*)&Qs[wave * 1024 + (c * 4 + quad) * 128 + l16 * 8];
      #pragma unroll
      for (int nt = 0; nt < 4; ++nt) {
        short8 bk8 = *(const short8*)&Ks[nt * 1024 + (c * 4 + quad) * 128 + l16 * 8];
        sacc[nt] = __builtin_amdgcn_mfma_f32_16x16x32_bf16(aq, bk8, sacc[nt], 0, 0, 0);
      }
    }

    float sc[4][4], mt[4];
    #pragma unroll
    for (int r = 0; r < 4; ++r) {
      int i_loc = wave * 16 + quad * 4 + r;
      int i_glob = it0 + i_loc;
      float g = gbuf[i_loc];
      float mx = -1e30f;
      #pragma unroll
      for (int nt = 0; nt < 4; ++nt) {
        int j = j0 + nt * 16 + l16;
        float s = sacc[nt][r] + g * bf2f(btl[j - i_glob + 1023]);
        sc[nt][r] = s;
        mx = fmaxf(mx, s);
      }
      mt[r] = mx;
    }
    #pragma unroll
    for (int m = 1; m < 16; m <<= 1)
      #pragma unroll
      for (int r = 0; r < 4; ++r) mt[r] = fmaxf(mt[r], __shfl_xor(mt[r], m, 64));

    float alpha[4], ls[4];
    #pragma unroll
    for (int r = 0; r < 4; ++r) {
      float mnew = fmaxf(mrow[r], mt[r]);
      alpha[r] = __expf(mrow[r] - mnew);
      mrow[r] = mnew;
      float lsum = 0.f;
      #pragma unroll
      for (int nt = 0; nt < 4; ++nt) {
        float p = __expf(sc[nt][r] - mnew);
        sc[nt][r] = p;
        lsum += p;
      }
      ls[r] = lsum;
    }
    #pragma unroll
    for (int m = 1; m < 16; m <<= 1)
      #pragma unroll
      for (int r = 0; r < 4; ++r) ls[r] += __shfl_xor(ls[r], m, 64);
    #pragma unroll
    for (int r = 0; r < 4; ++r) lrow[r] = lrow[r] * alpha[r] + ls[r];

    #pragma unroll
    for (int nt = 0; nt < 4; ++nt)
      #pragma unroll
      for (int r = 0; r < 4; ++r)
        Ps[wave][(nt * 2 + (l16 >> 3)) * 128 + (quad * 4 + r) * 8 + (l16 & 7)] = f2bf(sc[nt][r]);

    #pragma unroll
    for (int dt = 0; dt < 4; ++dt)
      #pragma unroll
      for (int r = 0; r < 4; ++r) oacc[dt][r] *= alpha[r];

    #pragma unroll
    for (int c = 0; c < 2; ++c) {
      short8 ap = *(const short8*)&Ps[wave][(c * 4 + quad) * 128 + l16 * 8];
      #pragma unroll
      for (int dt = 0; dt < 4; ++dt) {
        short8 bv8 = *(const short8*)&Vs[dt * 1024 + (c * 4 + quad) * 128 + l16 * 8];
        oacc[dt] = __builtin_amdgcn_mfma_f32_16x16x32_bf16(ap, bv8, oacc[dt], 0, 0, 0);
      }
    }
    __syncthreads();
  }

  #pragma unroll
  for (int dt = 0; dt < 4; ++dt)
    #pragma unroll
    for (int r = 0; r < 4; ++r) {
      int i_loc = wave * 16 + quad * 4 + r;
      int d = dt * 16 + l16;
      float o = oacc[dt][r] / lrow[r];
      ctxb[((size_t)(b * 1024 + it0 + i_loc)) * 1024 + h * 64 + d] = f2bf(o);
    }
}

// ---------- fused reduce(+resid+bias) + LayerNorm ----------
template <bool WRITE_BF16, bool TWO_BIAS>
__global__ __launch_bounds__(256) void redln_kernel(
    const float* __restrict__ p0, const float* __restrict__ p1,
    const float* __restrict__ extra, const float* __restrict__ bias,
    const float* __restrict__ bias2,
    const float* __restrict__ g, const float* __restrict__ bta,
    float* __restrict__ outf, u16* __restrict__ outb) {
  __shared__ float red[8];
  int row = blockIdx.x, tid = threadIdx.x;
  int lane = tid & 63, wave = tid >> 6;
  size_t base = (size_t)row * 1024 + tid * 4;
  float4 a = *(const float4*)&p0[base];
  float4 bb = *(const float4*)&p1[base];
  float4 c = *(const float4*)&extra[base];
  float4 d = *(const float4*)&bias[tid * 4];
  float4 v;
  v.x = a.x + bb.x + c.x + d.x;
  v.y = a.y + bb.y + c.y + d.y;
  v.z = a.z + bb.z + c.z + d.z;
  v.w = a.w + bb.w + c.w + d.w;
  if (TWO_BIAS) {
    float4 d2 = *(const float4*)&bias2[tid * 4];
    v.x += d2.x; v.y += d2.y; v.z += d2.z; v.w += d2.w;
  }
  float s = v.x + v.y + v.z + v.w;
  #pragma unroll
  for (int m = 1; m < 64; m <<= 1) s += __shfl_xor(s, m, 64);
  if (lane == 0) red[wave] = s;
  __syncthreads();
  float mean = (red[0] + red[1] + red[2] + red[3]) * (1.f / 1024.f);
  float d0 = v.x - mean, d1 = v.y - mean, d2 = v.z - mean, d3 = v.w - mean;
  float sq = d0 * d0 + d1 * d1 + d2 * d2 + d3 * d3;
  #pragma unroll
  for (int m = 1; m < 64; m <<= 1) sq += __shfl_xor(sq, m, 64);
  if (lane == 0) red[4 + wave] = sq;
  __syncthreads();
  float var = (red[4] + red[5] + red[6] + red[7]) * (1.f / 1024.f);
  float rstd = rsqrtf(var + 1e-5f);
  float dd[4] = {d0, d1, d2, d3};
  #pragma unroll
  for (int e = 0; e < 4; ++e) {
    int cidx = tid * 4 + e;
    float val = dd[e] * rstd * g[cidx] + bta[cidx];
    outf[(size_t)row * 1024 + cidx] = val;
    if (WRITE_BF16) outb[(size_t)row * 1024 + cidx] = f2bf(val);
  }
}

// ---------- launch ----------
extern "C" void kernel_launch(void* const* d_in, const int* in_sizes, int n_in,
                              void* d_out, int out_size, void* d_ws, size_t ws_size,
                              hipStream_t stream) {
  const float* x    = (const float*)d_in[0];
  const float* Wq   = (const float*)d_in[1];  const float* bq  = (const float*)d_in[2];
  const float* Wk   = (const float*)d_in[3];  const float* bk  = (const float*)d_in[4];
  const float* Wv   = (const float*)d_in[5];  const float* bv  = (const float*)d_in[6];
  const float* Wo   = (const float*)d_in[7];  const float* bo  = (const float*)d_in[8];
  const float* Wg   = (const float*)d_in[9];  const float* bg  = (const float*)d_in[10];
  const float* gc   = (const float*)d_in[11];
  const float* rel  = (const float*)d_in[12];
  const float* ln1g = (const float*)d_in[13]; const float* ln1b = (const float*)d_in[14];
  const float* W1   = (const float*)d_in[15]; const float* b1  = (const float*)d_in[16];
  const float* W2   = (const float*)d_in[17]; const float* b2  = (const float*)d_in[18];
  const float* ln2g = (const float*)d_in[19]; const float* ln2b = (const float*)d_in[20];
  const float* Wad  = (const float*)d_in[21]; const float* bad = (const float*)d_in[22];
  const float* Wau  = (const float*)d_in[23]; const float* bau = (const float*)d_in[24];
  float* out = (float*)d_out;

  char* ws = (char*)d_ws;
  const size_t MB = 1ull << 20;
  const size_t KB = 1ull << 10;
  // phase-overlaid layout, peak 118MB
  u16*   xb    = (u16*)(ws + 0 * MB);             // 8MB  [dead after QKV]
  u16*   wqkv  = (u16*)(ws + 8 * MB);             // 6MB  [dead after QKV]
  u16*   qb    = (u16*)(ws + 14 * MB);            // 8MB  [dead after attn]
  u16*   kb    = (u16*)(ws + 22 * MB);            // 8MB  [dead after attn]
  u16*   vbp   = (u16*)(ws + 30 * MB);            // 8MB  [dead after vtrans]
  u16*   vtb   = (u16*)(ws + 38 * MB);            // 8MB  [dead after attn]
  float* gate  = (float*)(ws + 46 * MB);          // 256KB [dead after attn]
  float* btab  = (float*)(ws + 46 * MB + 256 * KB); // 128KB [dead after attn]
  u16*   ffadp = (u16*)(ws + 0 * MB);             // 34MB [FF1->FF2', overlays 0..34]
  float* P0    = (float*)(ws + 34 * MB);          // 16MB partials
  float* P1    = (float*)(ws + 50 * MB);          // 16MB
  u16*   ctxb  = (u16*)(ws + 66 * MB);            // 8MB
  u16*   wob   = (u16*)(ws + 74 * MB);            // 2MB
  u16*   w1ad  = (u16*)(ws + 76 * MB);            // 8.5MB (W1|Wad)
  u16*   w2au  = (u16*)(ws + 85 * MB);            // 8.5MB (W2|Wau padded rows)
  float* hf    = (float*)(ws + 94 * MB);          // 16MB
  u16*   hb    = (u16*)(ws + 110 * MB);           // 8MB -> end 118MB
  (void)ws_size; (void)n_in; (void)in_sizes; (void)out_size;

  auto cvt = [&](const float* src, u16* dst, int n) {
    cvt_bf16<<<(n / 4 + 255) / 256, 256, 0, stream>>>(src, dst, n / 4);
  };
  cvt(x, xb, 4096 * 1024);
  cvt(Wq, wqkv,               1024 * 1024);
  cvt(Wk, wqkv + 1024 * 1024, 1024 * 1024);
  cvt(Wv, wqkv + 2 * 1024 * 1024, 1024 * 1024);
  cvt(Wo, wob, 1024 * 1024);
  cvt(W1, w1ad, 4096 * 1024);
  cvt(Wad, w1ad + 4096 * 1024, 256 * 1024);
  cvt_pad<<<(1024 * 1024 + 255) / 256, 256, 0, stream>>>(W2, w2au, 1024, 4352, 1024 * 1024);
  cvt_pad<<<(64 * 1024 + 255) / 256, 256, 0, stream>>>(Wau, w2au + 4096, 64, 4352, 64 * 1024);

  btab_kernel<<<128, 256, 0, stream>>>(rel, btab);
  gate_kernel<<<16384, 256, 0, stream>>>(x, Wg, bg, gc, gate);

  // QKV: M=4096 N=3072 K=1024
  gemm_bt<0><<<dim3(16, 24, 1), 256, 0, stream>>>(xb, wqkv, 1024, 1024, 3072,
      bq, bk, bv, nullptr, qb, kb, vbp);
  vtrans_kernel<<<dim3(16, 64), 256, 0, stream>>>(vbp, vtb);
  attn_kernel<<<dim3(16, 64), 256, 0, stream>>>(qb, kb, vtb, gate, btab, ctxb);
  // Wo split-K x2 -> P0,P1
  gemm_bt<3><<<dim3(16, 8, 2), 256, 0, stream>>>(ctxb, wob, 1024, 512, 1024,
      nullptr, nullptr, nullptr, P0, nullptr, nullptr, nullptr);
  // reduce + bo + residual(x) + LN1 -> hf/hb
  redln_kernel<true, false><<<4096, 256, 0, stream>>>(P0, P1, x, bo, nullptr,
      ln1g, ln1b, hf, hb);
  // FF1 + adapter-down: N=4352 -> ffadp (gelu | elu), row stride 4352
  gemm_bt<2><<<dim3(16, 34, 1), 256, 0, stream>>>(hb, w1ad, 1024, 1024, 4352,
      b1, bad, nullptr, nullptr, ffadp, nullptr, nullptr);
  // FF2+adapter-up fused via K-concat: K=4352, split-K x2 -> P0,P1
  gemm_bt<3><<<dim3(16, 8, 2), 256, 0, stream>>>(ffadp, w2au, 4352, 2176, 1024,
      nullptr, nullptr, nullptr, P0, nullptr, nullptr, nullptr);
  // reduce + b2 + bau + residual(hf) + LN2 -> out
  redln_kernel<false, true><<<4096, 256, 0, stream>>>(P0, P1, hf, b2, bau,
      ln2g, ln2b, out, nullptr);
}

// Round 5
// 535.294 us; speedup vs baseline: 1.1611x; 1.1611x over previous
//
#include <hip/hip_runtime.h>
#include <cmath>

typedef unsigned short u16;
using short8 = __attribute__((ext_vector_type(8))) short;   // 8 x bf16
using f32x4  = __attribute__((ext_vector_type(4))) float;   // MFMA acc

// ---------- helpers ----------
__device__ __forceinline__ u16 f2bf(float f) {  // fp32 -> bf16 RNE
  union { float f; unsigned u; } c; c.f = f;
  unsigned r = c.u + 0x7fffu + ((c.u >> 16) & 1u);
  return (u16)(r >> 16);
}
__device__ __forceinline__ float bf2f(u16 b) {
  union { unsigned u; float f; } c; c.u = ((unsigned)b) << 16;
  return c.f;
}

__device__ __forceinline__ void gld_lds16(void* lds, const void* g) {
  __builtin_amdgcn_global_load_lds(
      (const __attribute__((address_space(1))) void*)g,
      (__attribute__((address_space(3))) void*)lds, 16, 0, 0);
}

// fast GELU (tanh approx, max err ~1e-3 << bf16 threshold)
__device__ __forceinline__ float gelu_fast(float t) {
  float u = 0.7978845608f * t * (1.f + 0.044715f * t * t);
  float th = 1.f - 2.f / (__expf(2.f * u) + 1.f);
  return 0.5f * t * (1.f + th);
}

// ---------- fp32 -> bf16 convert ----------
__global__ __launch_bounds__(256) void cvt_bf16(const float* __restrict__ in,
                                                u16* __restrict__ out, int n4) {
  int i = blockIdx.x * 256 + threadIdx.x;
  if (i >= n4) return;
  float4 v = ((const float4*)in)[i];
  ushort4 o;
  o.x = f2bf(v.x); o.y = f2bf(v.y); o.z = f2bf(v.z); o.w = f2bf(v.w);
  ((ushort4*)out)[i] = o;
}

// fp32 -> bf16 into strided (padded) rows
__global__ __launch_bounds__(256) void cvt_pad(const float* __restrict__ in,
                                               u16* __restrict__ out,
                                               int incols4, int outstride, int n4) {
  int i = blockIdx.x * 256 + threadIdx.x;
  if (i >= n4) return;
  int row = i / incols4, c = i - row * incols4;
  float4 v = ((const float4*)in)[i];
  ushort4 o;
  o.x = f2bf(v.x); o.y = f2bf(v.y); o.z = f2bf(v.z); o.w = f2bf(v.w);
  *(ushort4*)&out[(size_t)row * outstride + c * 4] = o;
}

// ---------- relative-position bias table ----------
__global__ __launch_bounds__(256) void btab_kernel(const float* __restrict__ rel_embed,
                                                   float* __restrict__ btab) {
  int idx = blockIdx.x * 256 + threadIdx.x;
  if (idx >= 16 * 2048) return;
  int h = idx >> 11;
  int d = idx & 2047;
  if (d >= 2047) return;
  int rel = d - 1023;
  int bucket = (rel > 0) ? 160 : 0;
  int ar = rel < 0 ? -rel : rel;
  if (ar < 80) {
    bucket += ar;
  } else {
    int large = 80 + (int)(logf((float)ar / 80.0f) / 2.3025851f * 80.0f);
    if (large > 159) large = 159;
    bucket += large;
  }
  btab[h * 2048 + d] = rel_embed[bucket * 16 + h];
}

// ---------- gate ----------
__global__ __launch_bounds__(256) void gate_kernel(const float* __restrict__ x,
                                                   const float* __restrict__ Wg,
                                                   const float* __restrict__ bg,
                                                   const float* __restrict__ gc,
                                                   float* __restrict__ gate_out) {
  int gw = blockIdx.x * 4 + (threadIdx.x >> 6);
  int lane = threadIdx.x & 63;
  int s = gw & 1023, bh = gw >> 10, b = bh >> 4, h = bh & 15;
  float wA = Wg[lane] + Wg[64 + lane] + Wg[128 + lane] + Wg[192 + lane];
  float wB = Wg[256 + lane] + Wg[320 + lane] + Wg[384 + lane] + Wg[448 + lane];
  float xv = x[((size_t)(b * 1024 + s)) * 1024 + h * 64 + lane];
  float pa = xv * wA, pb = xv * wB;
  #pragma unroll
  for (int m = 1; m < 64; m <<= 1) {
    pa += __shfl_xor(pa, m, 64);
    pb += __shfl_xor(pb, m, 64);
  }
  if (lane == 0) {
    float bgA = bg[0] + bg[1] + bg[2] + bg[3];
    float bgB = bg[4] + bg[5] + bg[6] + bg[7];
    float ga = 1.f / (1.f + expf(-(pa + bgA)));
    float gb = 1.f / (1.f + expf(-(pb + bgB)));
    gate_out[(size_t)bh * 1024 + s] = ga * (gb * gc[h] - 1.f) + 2.f;
  }
}

// ---------- V transpose: vt[bh][d][s] ----------
__global__ __launch_bounds__(256) void vtrans_kernel(const u16* __restrict__ vb,
                                                     u16* __restrict__ vt) {
  __shared__ u16 tile[64 * 65];
  int bh = blockIdx.y, b = bh >> 4, h = bh & 15;
  int s0 = blockIdx.x * 64;
  int tid = threadIdx.x;
  int r = tid >> 3, c = (tid & 7) * 8;
  #pragma unroll
  for (int p = 0; p < 2; ++p) {
    int s = p * 32 + r;
    uint4 vv = *(const uint4*)&vb[((size_t)(b * 1024 + s0 + s)) * 1024 + h * 64 + c];
    const u16* pv = (const u16*)&vv;
    #pragma unroll
    for (int e = 0; e < 8; ++e) tile[(c + e) * 65 + s] = pv[e];
  }
  __syncthreads();
  int d = tid & 63, jc0 = tid >> 6;
  #pragma unroll
  for (int jc = jc0; jc < 8; jc += 4) {
    u16 tmp[8];
    #pragma unroll
    for (int e = 0; e < 8; ++e) tmp[e] = tile[d * 65 + jc * 8 + e];
    *(uint4*)&vt[((size_t)(bh * 64 + d)) * 1024 + s0 + jc * 8] = *(uint4*)tmp;
  }
}

// ---------- GEMM: 128x128 tile, 3-stage pipeline (depth-2 prefetch) ----------
// C[m,n] = sum_k A[m,k]*Bw[n,k]. 4 waves, each 64x64 (4x4 16x16 accs).
// 3 LDS buffers; loads for step ks+2 issued AFTER barrier(ks); mid-loop
// s_waitcnt vmcnt(4) (one step's 4 loads in flight). Single barrier per
// step is safe: buf[(ks+2)%3]'s last readers ran in iter ks-1, and their
// ds_reads complete before the MFMAs that precede barrier(ks).
// MODE 0: QKV (bias + q*0.125, bf16 x3)
// MODE 2: gelu/elu -> ffadp (stride 4352; branch block-uniform)
// MODE 3: fp32 partial store (z partials, stride 4M floats)
template <int MODE>
__global__ __launch_bounds__(256, 3) void gemm_bt(
    const u16* __restrict__ A, const u16* __restrict__ Bw,
    int K, int Ksub, int N,
    const float* __restrict__ bias0, const float* __restrict__ bias1,
    const float* __restrict__ bias2,
    float* __restrict__ outf,
    u16* __restrict__ ob0, u16* __restrict__ ob1, u16* __restrict__ ob2) {
  __shared__ __align__(16) u16 As[3][128 * 32];
  __shared__ __align__(16) u16 Bs[3][128 * 32];
  const int tid = threadIdx.x;
  const int lane = tid & 63, wave = tid >> 6;
  const int quad = lane >> 4, l16 = lane & 15;
  const int bm = blockIdx.x * 128, bn = blockIdx.y * 128;
  const int kz = blockIdx.z;
  const int nsteps = Ksub >> 5;
  const int wm = (wave & 1) * 64, wn = (wave >> 1) * 64;
  const int sr = lane & 15, skc = (lane >> 4) * 8;

  const u16* a0 = A + (size_t)(bm + wave * 32 + sr) * K + kz * Ksub + skc;
  const u16* b0 = Bw + (size_t)(bn + wave * 32 + sr) * K + kz * Ksub + skc;
  const size_t ra = (size_t)16 * K;

  f32x4 acc[4][4] = {};

  // prologue: steps 0,1 -> bufs 0,1
  #pragma unroll
  for (int t = 0; t < 2; ++t) {
    gld_lds16(&As[0][(wave * 2 + t) * 512], a0 + t * ra);
    gld_lds16(&Bs[0][(wave * 2 + t) * 512], b0 + t * ra);
  }
  if (nsteps > 1) {
    #pragma unroll
    for (int t = 0; t < 2; ++t) {
      gld_lds16(&As[1][(wave * 2 + t) * 512], a0 + t * ra + 32);
      gld_lds16(&Bs[1][(wave * 2 + t) * 512], b0 + t * ra + 32);
    }
  }

  int cur = 0, nxt2 = 2;
  for (int ks = 0; ks < nsteps; ++ks) {
    if (ks + 1 < nsteps) asm volatile("s_waitcnt vmcnt(4)" ::: "memory");
    else                 asm volatile("s_waitcnt vmcnt(0)" ::: "memory");
    __builtin_amdgcn_s_barrier();
    if (ks + 2 < nsteps) {
      int ko = (ks + 2) * 32;
      #pragma unroll
      for (int t = 0; t < 2; ++t) {
        gld_lds16(&As[nxt2][(wave * 2 + t) * 512], a0 + t * ra + ko);
        gld_lds16(&Bs[nxt2][(wave * 2 + t) * 512], b0 + t * ra + ko);
      }
    }
    const u16* Ap = As[cur];
    const u16* Bp = Bs[cur];
    short8 af[4], bf[4];
    #pragma unroll
    for (int mi = 0; mi < 4; ++mi)
      af[mi] = *(const short8*)&Ap[((wm >> 4) + mi) * 512 + quad * 128 + l16 * 8];
    #pragma unroll
    for (int ni = 0; ni < 4; ++ni)
      bf[ni] = *(const short8*)&Bp[((wn >> 4) + ni) * 512 + quad * 128 + l16 * 8];
    #pragma unroll
    for (int mi = 0; mi < 4; ++mi)
      #pragma unroll
      for (int ni = 0; ni < 4; ++ni)
        acc[mi][ni] = __builtin_amdgcn_mfma_f32_16x16x32_bf16(af[mi], bf[ni], acc[mi][ni], 0, 0, 0);
    cur = (cur == 2) ? 0 : cur + 1;
    nxt2 = (nxt2 == 2) ? 0 : nxt2 + 1;
  }

  float* outp = outf + (size_t)kz * 4194304;   // 16MB partial stride

  #pragma unroll
  for (int mi = 0; mi < 4; ++mi) {
    #pragma unroll
    for (int ni = 0; ni < 4; ++ni) {
      int col = bn + wn + ni * 16 + l16;
      #pragma unroll
      for (int r = 0; r < 4; ++r) {
        int m = bm + wm + mi * 16 + quad * 4 + r;
        float v = acc[mi][ni][r];
        if constexpr (MODE == 0) {
          int seg = col >> 10;
          int nloc = col & 1023;
          const float* bs = seg == 0 ? bias0 : (seg == 1 ? bias1 : bias2);
          u16* dst = seg == 0 ? ob0 : (seg == 1 ? ob1 : ob2);
          v += bs[nloc];
          if (seg == 0) v *= 0.125f;
          dst[(size_t)m * 1024 + nloc] = f2bf(v);
        } else if constexpr (MODE == 2) {
          if (col < 4096) {
            float t = v + bias0[col];
            ob0[(size_t)m * 4352 + col] = f2bf(gelu_fast(t));
          } else {
            float t = v + bias1[col - 4096];
            float e = t > 0.f ? t : (__expf(t) - 1.f);
            ob0[(size_t)m * 4352 + col] = f2bf(e);
          }
        } else {
          outp[(size_t)m * N + col] = v;
        }
      }
    }
  }
}

// ---------- flash attention (conflict-free LDS) ----------
__global__ __launch_bounds__(256) void attn_kernel(
    const u16* __restrict__ qb, const u16* __restrict__ kb, const u16* __restrict__ vt,
    const float* __restrict__ gate, const float* __restrict__ btab,
    u16* __restrict__ ctxb) {
  __shared__ __align__(16) u16 Qs[64 * 64];
  __shared__ __align__(16) u16 Ks[64 * 64];
  __shared__ __align__(16) u16 Vs[64 * 64];
  __shared__ __align__(16) u16 Ps[4][16 * 64];
  __shared__ u16 btl[2048];
  __shared__ float gbuf[64];

  const int tid = threadIdx.x;
  const int lane = tid & 63, wave = tid >> 6;
  const int quad = lane >> 4, l16 = lane & 15;
  const int it0 = blockIdx.x * 64;
  const int bh = blockIdx.y, b = bh >> 4, h = bh & 15;
  const int sr = lane & 15;
  const int skc = (lane >> 4) * 8;

  for (int idx = tid; idx < 2047; idx += 256) btl[idx] = f2bf(btab[h * 2048 + idx]);
  if (tid < 64) gbuf[tid] = gate[(size_t)bh * 1024 + it0 + tid];

  #pragma unroll
  for (int hf = 0; hf < 2; ++hf)
    gld_lds16(&Qs[wave * 1024 + hf * 512],
              &qb[((size_t)(b * 1024 + it0 + wave * 16 + sr)) * 1024 + h * 64 + hf * 32 + skc]);

  f32x4 oacc[4] = {};
  float mrow[4], lrow[4];
  #pragma unroll
  for (int r = 0; r < 4; ++r) { mrow[r] = -1e30f; lrow[r] = 0.f; }

  __syncthreads();

  for (int jt = 0; jt < 16; ++jt) {
    int j0 = jt * 64;
    #pragma unroll
    for (int hf = 0; hf < 2; ++hf) {
      gld_lds16(&Ks[wave * 1024 + hf * 512],
                &kb[((size_t)(b * 1024 + j0 + wave * 16 + sr)) * 1024 + h * 64 + hf * 32 + skc]);
      gld_lds16(&Vs[wave * 1024 + hf * 512],
                &vt[((size_t)(bh * 64 + wave * 16 + sr)) * 1024 + j0 + hf * 32 + skc]);
    }
    __syncthreads();

    f32x4 sacc[4] = {};
    #pragma unroll
    for (int c = 0; c < 2; ++c) {
      short8 aq = *(const short8*)&Qs[wave * 1024 + (c * 4 + quad) * 128 + l16 * 8];
      #pragma unroll
      for (int nt = 0; nt < 4; ++nt) {
        short8 bk8 = *(const short8*)&Ks[nt * 1024 + (c * 4 + quad) * 128 + l16 * 8];
        sacc[nt] = __builtin_amdgcn_mfma_f32_16x16x32_bf16(aq, bk8, sacc[nt], 0, 0, 0);
      }
    }

    float sc[4][4], mt[4];
    #pragma unroll
    for (int r = 0; r < 4; ++r) {
      int i_loc = wave * 16 + quad * 4 + r;
      int i_glob = it0 + i_loc;
      float g = gbuf[i_loc];
      float mx = -1e30f;
      #pragma unroll
      for (int nt = 0; nt < 4; ++nt) {
        int j = j0 + nt * 16 + l16;
        float s = sacc[nt][r] + g * bf2f(btl[j - i_glob + 1023]);
        sc[nt][r] = s;
        mx = fmaxf(mx, s);
      }
      mt[r] = mx;
    }
    #pragma unroll
    for (int m = 1; m < 16; m <<= 1)
      #pragma unroll
      for (int r = 0; r < 4; ++r) mt[r] = fmaxf(mt[r], __shfl_xor(mt[r], m, 64));

    float alpha[4], ls[4];
    #pragma unroll
    for (int r = 0; r < 4; ++r) {
      float mnew = fmaxf(mrow[r], mt[r]);
      alpha[r] = __expf(mrow[r] - mnew);
      mrow[r] = mnew;
      float lsum = 0.f;
      #pragma unroll
      for (int nt = 0; nt < 4; ++nt) {
        float p = __expf(sc[nt][r] - mnew);
        sc[nt][r] = p;
        lsum += p;
      }
      ls[r] = lsum;
    }
    #pragma unroll
    for (int m = 1; m < 16; m <<= 1)
      #pragma unroll
      for (int r = 0; r < 4; ++r) ls[r] += __shfl_xor(ls[r], m, 64);
    #pragma unroll
    for (int r = 0; r < 4; ++r) lrow[r] = lrow[r] * alpha[r] + ls[r];

    #pragma unroll
    for (int nt = 0; nt < 4; ++nt)
      #pragma unroll
      for (int r = 0; r < 4; ++r)
        Ps[wave][(nt * 2 + (l16 >> 3)) * 128 + (quad * 4 + r) * 8 + (l16 & 7)] = f2bf(sc[nt][r]);

    #pragma unroll
    for (int dt = 0; dt < 4; ++dt)
      #pragma unroll
      for (int r = 0; r < 4; ++r) oacc[dt][r] *= alpha[r];

    #pragma unroll
    for (int c = 0; c < 2; ++c) {
      short8 ap = *(const short8*)&Ps[wave][(c * 4 + quad) * 128 + l16 * 8];
      #pragma unroll
      for (int dt = 0; dt < 4; ++dt) {
        short8 bv8 = *(const short8*)&Vs[dt * 1024 + (c * 4 + quad) * 128 + l16 * 8];
        oacc[dt] = __builtin_amdgcn_mfma_f32_16x16x32_bf16(ap, bv8, oacc[dt], 0, 0, 0);
      }
    }
    __syncthreads();
  }

  #pragma unroll
  for (int dt = 0; dt < 4; ++dt)
    #pragma unroll
    for (int r = 0; r < 4; ++r) {
      int i_loc = wave * 16 + quad * 4 + r;
      int d = dt * 16 + l16;
      float o = oacc[dt][r] / lrow[r];
      ctxb[((size_t)(b * 1024 + it0 + i_loc)) * 1024 + h * 64 + d] = f2bf(o);
    }
}

// ---------- fused reduce(+resid+bias) + LayerNorm ----------
template <bool WRITE_BF16, bool TWO_BIAS>
__global__ __launch_bounds__(256) void redln_kernel(
    const float* __restrict__ p0, const float* __restrict__ p1,
    const float* __restrict__ extra, const float* __restrict__ bias,
    const float* __restrict__ bias2,
    const float* __restrict__ g, const float* __restrict__ bta,
    float* __restrict__ outf, u16* __restrict__ outb) {
  __shared__ float red[8];
  int row = blockIdx.x, tid = threadIdx.x;
  int lane = tid & 63, wave = tid >> 6;
  size_t base = (size_t)row * 1024 + tid * 4;
  float4 a = *(const float4*)&p0[base];
  float4 bb = *(const float4*)&p1[base];
  float4 c = *(const float4*)&extra[base];
  float4 d = *(const float4*)&bias[tid * 4];
  float4 v;
  v.x = a.x + bb.x + c.x + d.x;
  v.y = a.y + bb.y + c.y + d.y;
  v.z = a.z + bb.z + c.z + d.z;
  v.w = a.w + bb.w + c.w + d.w;
  if (TWO_BIAS) {
    float4 d2 = *(const float4*)&bias2[tid * 4];
    v.x += d2.x; v.y += d2.y; v.z += d2.z; v.w += d2.w;
  }
  float s = v.x + v.y + v.z + v.w;
  #pragma unroll
  for (int m = 1; m < 64; m <<= 1) s += __shfl_xor(s, m, 64);
  if (lane == 0) red[wave] = s;
  __syncthreads();
  float mean = (red[0] + red[1] + red[2] + red[3]) * (1.f / 1024.f);
  float d0 = v.x - mean, d1 = v.y - mean, d2 = v.z - mean, d3 = v.w - mean;
  float sq = d0 * d0 + d1 * d1 + d2 * d2 + d3 * d3;
  #pragma unroll
  for (int m = 1; m < 64; m <<= 1) sq += __shfl_xor(sq, m, 64);
  if (lane == 0) red[4 + wave] = sq;
  __syncthreads();
  float var = (red[4] + red[5] + red[6] + red[7]) * (1.f / 1024.f);
  float rstd = rsqrtf(var + 1e-5f);
  float dd[4] = {d0, d1, d2, d3};
  #pragma unroll
  for (int e = 0; e < 4; ++e) {
    int cidx = tid * 4 + e;
    float val = dd[e] * rstd * g[cidx] + bta[cidx];
    outf[(size_t)row * 1024 + cidx] = val;
    if (WRITE_BF16) outb[(size_t)row * 1024 + cidx] = f2bf(val);
  }
}

// ---------- launch ----------
extern "C" void kernel_launch(void* const* d_in, const int* in_sizes, int n_in,
                              void* d_out, int out_size, void* d_ws, size_t ws_size,
                              hipStream_t stream) {
  const float* x    = (const float*)d_in[0];
  const float* Wq   = (const float*)d_in[1];  const float* bq  = (const float*)d_in[2];
  const float* Wk   = (const float*)d_in[3];  const float* bk  = (const float*)d_in[4];
  const float* Wv   = (const float*)d_in[5];  const float* bv  = (const float*)d_in[6];
  const float* Wo   = (const float*)d_in[7];  const float* bo  = (const float*)d_in[8];
  const float* Wg   = (const float*)d_in[9];  const float* bg  = (const float*)d_in[10];
  const float* gc   = (const float*)d_in[11];
  const float* rel  = (const float*)d_in[12];
  const float* ln1g = (const float*)d_in[13]; const float* ln1b = (const float*)d_in[14];
  const float* W1   = (const float*)d_in[15]; const float* b1  = (const float*)d_in[16];
  const float* W2   = (const float*)d_in[17]; const float* b2  = (const float*)d_in[18];
  const float* ln2g = (const float*)d_in[19]; const float* ln2b = (const float*)d_in[20];
  const float* Wad  = (const float*)d_in[21]; const float* bad = (const float*)d_in[22];
  const float* Wau  = (const float*)d_in[23]; const float* bau = (const float*)d_in[24];
  float* out = (float*)d_out;

  char* ws = (char*)d_ws;
  const size_t MB = 1ull << 20;
  const size_t KB = 1ull << 10;
  // phase-overlaid layout, peak 118MB
  u16*   xb    = (u16*)(ws + 0 * MB);             // 8MB  [dead after QKV]
  u16*   wqkv  = (u16*)(ws + 8 * MB);             // 6MB  [dead after QKV]
  u16*   qb    = (u16*)(ws + 14 * MB);            // 8MB  [dead after attn]
  u16*   kb    = (u16*)(ws + 22 * MB);            // 8MB  [dead after attn]
  u16*   vbp   = (u16*)(ws + 30 * MB);            // 8MB  [dead after vtrans]
  u16*   vtb   = (u16*)(ws + 38 * MB);            // 8MB  [dead after attn]
  float* gate  = (float*)(ws + 46 * MB);          // 256KB [dead after attn]
  float* btab  = (float*)(ws + 46 * MB + 256 * KB); // 128KB [dead after attn]
  u16*   ffadp = (u16*)(ws + 0 * MB);             // 34MB [FF1->FF2', overlays 0..34]
  float* P0    = (float*)(ws + 34 * MB);          // 16MB partials
  float* P1    = (float*)(ws + 50 * MB);          // 16MB
  u16*   ctxb  = (u16*)(ws + 66 * MB);            // 8MB
  u16*   wob   = (u16*)(ws + 74 * MB);            // 2MB
  u16*   w1ad  = (u16*)(ws + 76 * MB);            // 8.5MB (W1|Wad)
  u16*   w2au  = (u16*)(ws + 85 * MB);            // 8.5MB (W2|Wau padded rows)
  float* hf    = (float*)(ws + 94 * MB);          // 16MB
  u16*   hb    = (u16*)(ws + 110 * MB);           // 8MB -> end 118MB
  (void)ws_size; (void)n_in; (void)in_sizes; (void)out_size;

  auto cvt = [&](const float* src, u16* dst, int n) {
    cvt_bf16<<<(n / 4 + 255) / 256, 256, 0, stream>>>(src, dst, n / 4);
  };
  cvt(x, xb, 4096 * 1024);
  cvt(Wq, wqkv,               1024 * 1024);
  cvt(Wk, wqkv + 1024 * 1024, 1024 * 1024);
  cvt(Wv, wqkv + 2 * 1024 * 1024, 1024 * 1024);
  cvt(Wo, wob, 1024 * 1024);
  cvt(W1, w1ad, 4096 * 1024);
  cvt(Wad, w1ad + 4096 * 1024, 256 * 1024);
  cvt_pad<<<(1024 * 1024 + 255) / 256, 256, 0, stream>>>(W2, w2au, 1024, 4352, 1024 * 1024);
  cvt_pad<<<(64 * 1024 + 255) / 256, 256, 0, stream>>>(Wau, w2au + 4096, 64, 4352, 64 * 1024);

  btab_kernel<<<128, 256, 0, stream>>>(rel, btab);
  gate_kernel<<<16384, 256, 0, stream>>>(x, Wg, bg, gc, gate);

  // QKV: M=4096 N=3072 K=1024
  gemm_bt<0><<<dim3(32, 24, 1), 256, 0, stream>>>(xb, wqkv, 1024, 1024, 3072,
      bq, bk, bv, nullptr, qb, kb, vbp);
  vtrans_kernel<<<dim3(16, 64), 256, 0, stream>>>(vbp, vtb);
  attn_kernel<<<dim3(16, 64), 256, 0, stream>>>(qb, kb, vtb, gate, btab, ctxb);
  // Wo split-K x2 -> P0,P1
  gemm_bt<3><<<dim3(32, 8, 2), 256, 0, stream>>>(ctxb, wob, 1024, 512, 1024,
      nullptr, nullptr, nullptr, P0, nullptr, nullptr, nullptr);
  // reduce + bo + residual(x) + LN1 -> hf/hb
  redln_kernel<true, false><<<4096, 256, 0, stream>>>(P0, P1, x, bo, nullptr,
      ln1g, ln1b, hf, hb);
  // FF1 + adapter-down: N=4352 -> ffadp (gelu | elu), row stride 4352
  gemm_bt<2><<<dim3(32, 34, 1), 256, 0, stream>>>(hb, w1ad, 1024, 1024, 4352,
      b1, bad, nullptr, nullptr, ffadp, nullptr, nullptr);
  // FF2+adapter-up fused via K-concat: K=4352, split-K x2 -> P0,P1
  gemm_bt<3><<<dim3(32, 8, 2), 256, 0, stream>>>(ffadp, w2au, 4352, 2176, 1024,
      nullptr, nullptr, nullptr, P0, nullptr, nullptr, nullptr);
  // reduce + b2 + bau + residual(hf) + LN2 -> out
  redln_kernel<false, true><<<4096, 256, 0, stream>>>(P0, P1, hf, b2, bau,
      ln2g, ln2b, out, nullptr);
}